// Round 10
// baseline (165.722 us; speedup 1.0000x reference)
//
#include <hip/hip_runtime.h>
#include <hip/hip_bf16.h>

typedef __attribute__((ext_vector_type(8))) short s16x8;
typedef __attribute__((ext_vector_type(4))) float f32x4;

#define BB 16
#define LL 2048
#define HH 768
#define DD 768
#define MM 8

// d_out layout (float elements)
#define O_LOGITS 0
#define O_BID    128
#define O_LID    256
#define O_AGGL   384
#define O_SCALE  98688
#define O_AGGT   98689

// ws layout (bytes)
#define WTT_OFF  0u          // Wt^T bf16 768*768*2
#define WLT_OFF  1179648u    // Wl^T bf16
#define WTB_OFF  2359296u    // Wt bf16 (natural)
#define HBAR_OFF 3538944u    // 128*768 fp32
#define QH_OFF   3932160u    // 128*768 fp32
#define HST_OFF  4325376u    // 128*768 fp32
#define CVEC_OFF 4718592u    // 128 fp32
#define SC_OFF   4719104u    // 128*2048 fp32
#define PART_OFF 5767680u    // 8*128*768 fp32

__device__ __forceinline__ short f2bf(float x) {
  union { float f; unsigned u; } v; v.f = x;
  unsigned r = v.u + 0x7FFFu + ((v.u >> 16) & 1u);
  return (short)(r >> 16);
}

// async global->LDS, 16B per lane; LDS dest is wave-uniform base (HW adds lane*16)
#define GLOAD_LDS16(gp, lp) __builtin_amdgcn_global_load_lds( \
    (const __attribute__((address_space(1))) unsigned int*)(gp), \
    (__attribute__((address_space(3))) unsigned int*)(lp), 16, 0, 0)

// ---------------------------------------------------------------- W converts
// z=0: Wtt = Wt^T bf16; z=1: Wlt = Wl^T bf16; z=2: Wtb = Wt bf16 (no transpose)
__global__ void k_wcvt(const float* __restrict__ Wt, const float* __restrict__ Wl,
                       short* __restrict__ Wtt, short* __restrict__ Wlt,
                       short* __restrict__ Wtb) {
  __shared__ float tile[64][65];
  int z = blockIdx.z;
  int kb = blockIdx.x * 64;
  int nb = blockIdx.y * 64;
  int t = threadIdx.x;
  int c = t & 63;
  int r0 = (t >> 6) * 16;
  if (z == 2) {
#pragma unroll
    for (int i = 0; i < 16; ++i) {
      int r = kb + r0 + i;
      Wtb[(size_t)r * DD + nb + c] = f2bf(Wt[(size_t)r * DD + nb + c]);
    }
    return;
  }
  const float* src = z ? Wl : Wt;
  short* dst = z ? Wlt : Wtt;
#pragma unroll
  for (int i = 0; i < 16; ++i)
    tile[r0 + i][c] = src[(size_t)(kb + r0 + i) * DD + nb + c];
  __syncthreads();
#pragma unroll
  for (int i = 0; i < 16; ++i)
    dst[(size_t)(nb + r0 + i) * HH + kb + c] = f2bf(tile[c][r0 + i]);
}

// ---------------------------------------------------------------- hbar = segment-mean of hs
__global__ void k_hbar(const float* __restrict__ hs, const int* __restrict__ lmask,
                       float* __restrict__ hbar) {
  int b = blockIdx.x >> 3, m = blockIdx.x & 7;
  int t = threadIdx.x;
  int lane = t & 63, w = t >> 6;
  __shared__ int list[LL];
  __shared__ int nlist_s;
  if (w == 0) {  // deterministic compaction of matching token indices
    int base = 0;
    for (int win = 0; win < LL / 64; ++win) {
      int l = win * 64 + lane;
      bool match = (lmask[b * LL + l] == m + 1);
      unsigned long long mk = __ballot(match);
      if (match) {
        int pos = base + (int)__popcll(mk & ((1ull << lane) - 1ull));
        list[pos] = l;
      }
      base += (int)__popcll(mk);
    }
    if (lane == 0) nlist_s = base;
  }
  __syncthreads();
  int n = nlist_s;
  float inv = 1.0f / (float)(n > 1 ? n : 1);
  float a0 = 0.f, a1 = 0.f, a2 = 0.f;
  for (int i = 0; i < n; ++i) {
    const float* r = hs + (size_t)(b * LL + list[i]) * HH;
    a0 += r[t]; a1 += r[t + 256]; a2 += r[t + 512];
  }
  float* dst = hbar + (size_t)(b * MM + m) * HH;
  dst[t] = a0 * inv; dst[t + 256] = a1 * inv; dst[t + 512] = a2 * inv;
}

// ---------------------------------------------------------------- shared GEMM body (proven r6/r9)
#define Bb_M 128
#define Bb_N 128
#define Bb_K 64
#define NTK 12

struct GemmAcc { f32x4 acc[4][4]; };

__device__ __forceinline__ void gemm_body(
    short* AsB, short* BsB,
    const float* A, const short* Bt, int m0, int n0, int lda_k,
    GemmAcc& g, int t) {
  int lane = t & 63;
  int w = t >> 6;
  int wm = w >> 1, wn = w & 1;

  float4 areg[8];

  auto issueA = [&](int kt) {
    const float* Ag = A + (size_t)m0 * lda_k + kt * Bb_K;
#pragma unroll
    for (int i = 0; i < 8; ++i) {
      int slot = i * 256 + t;
      int row = slot >> 4, c = slot & 15;
      areg[i] = *(const float4*)(Ag + (size_t)row * lda_k + c * 4);
    }
  };
  auto issueB = [&](int kt, int buf) {
    const short* Bg = Bt + (size_t)n0 * lda_k + kt * Bb_K;
#pragma unroll
    for (int i = 0; i < 4; ++i) {
      int slot = i * 256 + w * 64 + lane;
      int row = slot >> 3, c = slot & 7;
      int cs = c ^ (row & 7);
      GLOAD_LDS16(Bg + (size_t)row * lda_k + cs * 8,
                  (char*)BsB + (size_t)buf * 16384 + (size_t)(i * 256 + w * 64) * 16);
    }
  };
  auto writeA = [&]() {
#pragma unroll
    for (int i = 0; i < 8; ++i) {
      int slot = i * 256 + t;
      int row = slot >> 4, c = slot & 15;
      unsigned d0, d1;
      asm("v_cvt_pk_bf16_f32 %0, %1, %2" : "=v"(d0) : "v"(areg[i].x), "v"(areg[i].y));
      asm("v_cvt_pk_bf16_f32 %0, %1, %2" : "=v"(d1) : "v"(areg[i].z), "v"(areg[i].w));
      int phys = (c >> 1) ^ (row & 7);
      uint2 val = {d0, d1};
      *(uint2*)((char*)AsB + (size_t)row * 128 + phys * 16 + (c & 1) * 8) = val;
    }
  };
  auto compute = [&](int buf) {
#pragma unroll
    for (int kk = 0; kk < 2; ++kk) {
      s16x8 a[4], bb[4];
#pragma unroll
      for (int i = 0; i < 4; ++i) {
        int row = wm * 64 + i * 16 + (lane & 15);
        int p = (kk * 4 + (lane >> 4)) ^ (row & 7);
        a[i] = *(const s16x8*)((const char*)AsB + (size_t)row * 128 + p * 16);
      }
#pragma unroll
      for (int i = 0; i < 4; ++i) {
        int row = wn * 64 + i * 16 + (lane & 15);
        int p = (kk * 4 + (lane >> 4)) ^ (row & 7);
        bb[i] = *(const s16x8*)((const char*)BsB + (size_t)buf * 16384 + (size_t)row * 128 + p * 16);
      }
#pragma unroll
      for (int mi = 0; mi < 4; ++mi)
#pragma unroll
        for (int ni = 0; ni < 4; ++ni)
          g.acc[mi][ni] = __builtin_amdgcn_mfma_f32_16x16x32_bf16(a[mi], bb[ni], g.acc[mi][ni], 0, 0, 0);
    }
  };

  issueA(0); issueB(0, 0);
  writeA();
  __syncthreads();
  for (int kt = 0; kt < NTK; ++kt) {
    if (kt + 1 < NTK) { issueA(kt + 1); issueB(kt + 1, (kt + 1) & 1); }
    compute(kt & 1);
    __syncthreads();
    if (kt + 1 < NTK) {
      writeA();
      __syncthreads();
    }
  }
}

// ---------------------------------------------------------------- agg = hbar @ Wl^T + bl -> out
__global__ __launch_bounds__(256, 3)
void k_gemm_agg(const float* __restrict__ hbar, const short* __restrict__ Wlt,
                const float* __restrict__ bl, float* __restrict__ out) {
  __shared__ short As[Bb_M][Bb_K];
  __shared__ short Bs[2][Bb_N][Bb_K];
  int t = threadIdx.x;
  int lane = t & 63, w = t >> 6;
  int wm = w >> 1, wn = w & 1;
  int n0 = blockIdx.x * Bb_N;

  GemmAcc g = {};
  gemm_body(&As[0][0], &Bs[0][0][0], hbar, Wlt, 0, n0, HH, g, t);

#pragma unroll
  for (int mi = 0; mi < 4; ++mi) {
    int row = wm * 64 + mi * 16 + ((lane >> 4) * 4);
#pragma unroll
    for (int ni = 0; ni < 4; ++ni) {
      int col = n0 + wn * 64 + ni * 16 + (lane & 15);
      float bv = bl[col];
#pragma unroll
      for (int j = 0; j < 4; ++j)
        out[O_AGGL + (size_t)(row + j) * DD + col] = g.acc[mi][ni][j] + bv;
    }
  }
}

// ---------------------------------------------------------------- qh = agg @ Wt^T ; cvec = agg . bt
__global__ __launch_bounds__(256, 3)
void k_qh(const float* __restrict__ out, const short* __restrict__ Wtb,
          const float* __restrict__ bt, float* __restrict__ qh, float* __restrict__ cvec) {
  const float* agg = out + O_AGGL;
  if (blockIdx.x == 6) {          // cvec block (no barriers)
    int t = threadIdx.x;
    if (t < 128) {
      float s = 0.f;
#pragma unroll 4
      for (int d = 0; d < DD; ++d) s += agg[(size_t)t * DD + d] * bt[d];
      cvec[t] = s;
    }
    return;
  }
  __shared__ short As[Bb_M][Bb_K];
  __shared__ short Bs[2][Bb_N][Bb_K];
  int t = threadIdx.x;
  int lane = t & 63, w = t >> 6;
  int wm = w >> 1, wn = w & 1;
  int n0 = blockIdx.x * Bb_N;

  GemmAcc g = {};
  gemm_body(&As[0][0], &Bs[0][0][0], agg, Wtb, 0, n0, DD, g, t);

#pragma unroll
  for (int mi = 0; mi < 4; ++mi) {
    int row = wm * 64 + mi * 16 + ((lane >> 4) * 4);
#pragma unroll
    for (int ni = 0; ni < 4; ++ni) {
      int col = n0 + wn * 64 + ni * 16 + (lane & 15);
#pragma unroll
      for (int j = 0; j < 4; ++j)
        qh[(size_t)(row + j) * HH + col] = g.acc[mi][ni][j];
    }
  }
}

// ---------------------------------------------------------------- scores = hs . qh + c (masked, /temp)
__global__ __launch_bounds__(256)
void k_scores2(const float* __restrict__ hs, const float* __restrict__ qh,
               const float* __restrict__ cvec, const int* __restrict__ lmask,
               const int* __restrict__ amask, const float* __restrict__ temp_p,
               float* __restrict__ scores) {
  int chunk = blockIdx.x;   // 32 chunks of 64 tokens
  int b = blockIdx.y;       // 16
  int t = threadIdx.x;
  int w = t >> 6, lane = t & 63;
  __shared__ float qh_l[MM][HH];
  __shared__ float c_l[MM];
  const float* qsrc = qh + (size_t)b * MM * HH;
  for (int i = t; i < MM * HH / 4; i += 256)
    *(float4*)&qh_l[0][i * 4] = *(const float4*)&qsrc[i * 4];
  if (t < MM) c_l[t] = cvec[b * MM + t];
  __syncthreads();
  float inv_temp = 1.0f / fmaxf(fabsf(temp_p[0]), 0.1f);
  for (int i = 0; i < 16; ++i) {
    int l = chunk * 64 + w * 16 + i;
    int is_text = (lmask[b * LL + l] == 0) && (amask[b * LL + l] == 1);
    float acc8[8] = {};
    if (is_text) {
      const float* hrow = hs + (size_t)(b * LL + l) * HH;
#pragma unroll
      for (int c = 0; c < 3; ++c) {
        float4 hv = *(const float4*)&hrow[c * 256 + lane * 4];
#pragma unroll
        for (int m = 0; m < 8; ++m) {
          float4 qv = *(const float4*)&qh_l[m][c * 256 + lane * 4];
          acc8[m] += hv.x * qv.x + hv.y * qv.y + hv.z * qv.z + hv.w * qv.w;
        }
      }
#pragma unroll
      for (int m = 0; m < 8; ++m) {
        float v = acc8[m];
        for (int s = 32; s; s >>= 1) v += __shfl_xor(v, s, 64);
        acc8[m] = v;
      }
    }
    if (lane == 0) {
#pragma unroll
      for (int m = 0; m < 8; ++m)
        scores[(size_t)(b * MM + m) * LL + l] =
            is_text ? (acc8[m] + c_l[m]) * inv_temp : -1e30f;
    }
  }
}

// ---------------------------------------------------------------- row softmax (in place)
__global__ void k_softmax(float* __restrict__ scores) {
  int row = blockIdx.x;
  float* s = scores + (size_t)row * LL;
  int t = threadIdx.x;
  int w = t >> 6, lane = t & 63;
  float v[8];
  float mx = -1e30f;
#pragma unroll
  for (int i = 0; i < 8; ++i) { v[i] = s[t + 256 * i]; mx = fmaxf(mx, v[i]); }
  for (int sh = 32; sh; sh >>= 1) mx = fmaxf(mx, __shfl_xor(mx, sh, 64));
  __shared__ float wred[4];
  __shared__ float wsum[4];
  if (lane == 0) wred[w] = mx;
  __syncthreads();
  mx = fmaxf(fmaxf(wred[0], wred[1]), fmaxf(wred[2], wred[3]));
  float sum = 0.f;
#pragma unroll
  for (int i = 0; i < 8; ++i) { v[i] = __expf(v[i] - mx); sum += v[i]; }
  for (int sh = 32; sh; sh >>= 1) sum += __shfl_xor(sum, sh, 64);
  if (lane == 0) wsum[w] = sum;
  __syncthreads();
  sum = wsum[0] + wsum[1] + wsum[2] + wsum[3];
  float inv = 1.0f / sum;
#pragma unroll
  for (int i = 0; i < 8; ++i) s[t + 256 * i] = v[i] * inv;
}

// ---------------------------------------------------------------- hst partials = attn-pool of hs
__global__ void k_pool(const float* __restrict__ hs, const float* __restrict__ attn,
                       float* __restrict__ part) {
  int lc = blockIdx.x;   // 8 chunks of 256 tokens
  int ht = blockIdx.y;   // 6 tiles of 128 h
  int b  = blockIdx.z;   // 16
  int t = threadIdx.x;
  int m  = t >> 5;
  int c4 = t & 31;
  __shared__ float at_l[MM][256];
  for (int i = t; i < MM * 256; i += 256) {
    int mm = i >> 8, ll = i & 255;
    at_l[mm][ll] = attn[(size_t)(b * MM + mm) * LL + lc * 256 + ll];
  }
  __syncthreads();
  float ax = 0.f, ay = 0.f, az = 0.f, aw = 0.f;
  const float* p = hs + (size_t)(b * LL + lc * 256) * HH + ht * 128 + c4 * 4;
#pragma unroll 4
  for (int ll = 0; ll < 256; ++ll) {
    float4 hv = *(const float4*)(p + (size_t)ll * HH);
    float a = at_l[m][ll];
    ax += a * hv.x; ay += a * hv.y; az += a * hv.z; aw += a * hv.w;
  }
  float4 acc = {ax, ay, az, aw};
  *(float4*)&part[((size_t)(lc * BB + b) * MM + m) * HH + ht * 128 + c4 * 4] = acc;
}

// ---------------------------------------------------------------- hst = sum of partials
__global__ void k_sumhst(const float* __restrict__ part, float* __restrict__ hst) {
  int idx4 = blockIdx.x * 256 + threadIdx.x;   // 24576 float4
  float4 s = {0.f, 0.f, 0.f, 0.f};
#pragma unroll
  for (int lc = 0; lc < 8; ++lc) {
    float4 v = *(const float4*)&part[(size_t)lc * 98304 + (size_t)idx4 * 4];
    s.x += v.x; s.y += v.y; s.z += v.z; s.w += v.w;
  }
  *(float4*)&hst[(size_t)idx4 * 4] = s;
}

// ---------------------------------------------------------------- aggregated_text = hst @ Wt + bt -> out
__global__ __launch_bounds__(256, 3)
void k_aggt(const float* __restrict__ hst, const short* __restrict__ Wtt,
            const float* __restrict__ bt, float* __restrict__ out) {
  __shared__ short As[Bb_M][Bb_K];
  __shared__ short Bs[2][Bb_N][Bb_K];
  int t = threadIdx.x;
  int lane = t & 63, w = t >> 6;
  int wm = w >> 1, wn = w & 1;
  int n0 = blockIdx.x * Bb_N;

  GemmAcc g = {};
  gemm_body(&As[0][0], &Bs[0][0][0], hst, Wtt, 0, n0, HH, g, t);

#pragma unroll
  for (int mi = 0; mi < 4; ++mi) {
    int row = wm * 64 + mi * 16 + ((lane >> 4) * 4);
#pragma unroll
    for (int ni = 0; ni < 4; ++ni) {
      int col = n0 + wn * 64 + ni * 16 + (lane & 15);
      float bv = bt[col];
#pragma unroll
      for (int j = 0; j < 4; ++j)
        out[O_AGGT + (size_t)(row + j) * DD + col] = g.acc[mi][ni][j] + bv;
    }
  }
}

// ---------------------------------------------------------------- cosine head + ids + scale
__global__ void k_head(const float* __restrict__ lscale_p, float* __restrict__ out) {
  int row = blockIdx.x;   // 128
  int lane = threadIdx.x; // 64
  const float* at = out + O_AGGT + (size_t)row * DD;
  const float* al = out + O_AGGL + (size_t)row * DD;
  float dot = 0.f, nt = 0.f, nl = 0.f;
  for (int i = lane; i < DD; i += 64) {
    float a = at[i], c = al[i];
    dot += a * c; nt += a * a; nl += c * c;
  }
  for (int s = 32; s; s >>= 1) {
    dot += __shfl_xor(dot, s, 64);
    nt  += __shfl_xor(nt, s, 64);
    nl  += __shfl_xor(nl, s, 64);
  }
  if (lane == 0) {
    float scale = expf(lscale_p[0]);
    float denom = fmaxf(sqrtf(nt), 1e-8f) * fmaxf(sqrtf(nl), 1e-8f);
    out[O_LOGITS + row] = dot / denom * scale;
    out[O_BID + row] = (float)(row >> 3);
    out[O_LID + row] = (float)((row & 7) + 1);
    if (row == 0) out[O_SCALE] = scale;
  }
}

extern "C" void kernel_launch(void* const* d_in, const int* in_sizes, int n_in,
                              void* d_out, int out_size, void* d_ws, size_t ws_size,
                              hipStream_t stream) {
  const float* hs    = (const float*)d_in[0];
  const float* Wt    = (const float*)d_in[1];
  const float* bt    = (const float*)d_in[2];
  const float* Wl    = (const float*)d_in[3];
  const float* bl    = (const float*)d_in[4];
  const float* atemp = (const float*)d_in[5];
  const float* lsc   = (const float*)d_in[6];
  const int*   lmask = (const int*)d_in[7];
  const int*   amask = (const int*)d_in[9];
  float* out = (float*)d_out;
  char* ws = (char*)d_ws;
  short* Wtt  = (short*)(ws + WTT_OFF);
  short* Wlt  = (short*)(ws + WLT_OFF);
  short* Wtb  = (short*)(ws + WTB_OFF);
  float* hbar = (float*)(ws + HBAR_OFF);
  float* qh   = (float*)(ws + QH_OFF);
  float* hst  = (float*)(ws + HST_OFF);
  float* cvec = (float*)(ws + CVEC_OFF);
  float* scores = (float*)(ws + SC_OFF);
  float* part   = (float*)(ws + PART_OFF);

  k_wcvt<<<dim3(12, 12, 3), 256, 0, stream>>>(Wt, Wl, Wtt, Wlt, Wtb);
  k_hbar<<<128, 256, 0, stream>>>(hs, lmask, hbar);
  k_gemm_agg<<<6, 256, 0, stream>>>(hbar, Wlt, bl, out);
  k_qh<<<7, 256, 0, stream>>>(out, Wtb, bt, qh, cvec);
  k_scores2<<<dim3(32, 16), 256, 0, stream>>>(hs, qh, cvec, lmask, amask, atemp, scores);
  k_softmax<<<128, 256, 0, stream>>>(scores);
  k_pool<<<dim3(8, 6, 16), 256, 0, stream>>>(hs, scores, part);
  k_sumhst<<<96, 256, 0, stream>>>(part, hst);
  k_aggt<<<6, 256, 0, stream>>>(hst, Wtt, bt, out);
  k_head<<<128, 64, 0, stream>>>(lsc, out);
}

// Round 11
// 142.602 us; speedup vs baseline: 1.1621x; 1.1621x over previous
//
#include <hip/hip_runtime.h>
#include <hip/hip_bf16.h>

typedef __attribute__((ext_vector_type(8))) short s16x8;
typedef __attribute__((ext_vector_type(4))) float f32x4;

#define BB 16
#define LL 2048
#define HH 768
#define DD 768
#define MM 8

// d_out layout (float elements)
#define O_LOGITS 0
#define O_BID    128
#define O_LID    256
#define O_AGGL   384
#define O_SCALE  98688
#define O_AGGT   98689

// ws layout (bytes)
#define WTT_OFF  0u          // Wt^T bf16 768*768*2
#define WLT_OFF  1179648u    // Wl^T bf16
#define WTB_OFF  2359296u    // Wt bf16 (natural)
#define HBAR_OFF 3538944u    // 128*768 fp32
#define QH_OFF   3932160u    // 128*768 fp32
#define HST_OFF  4325376u    // 128*768 fp32
#define CVEC_OFF 4718592u    // 128 fp32
#define SC_OFF   4719104u    // 128*2048 fp32
#define PART_OFF 5767680u    // 8*128*768 fp32

__device__ __forceinline__ short f2bf(float x) {
  union { float f; unsigned u; } v; v.f = x;
  unsigned r = v.u + 0x7FFFu + ((v.u >> 16) & 1u);
  return (short)(r >> 16);
}

// async global->LDS, 16B per lane; LDS dest is wave-uniform base (HW adds lane*16)
#define GLOAD_LDS16(gp, lp) __builtin_amdgcn_global_load_lds( \
    (const __attribute__((address_space(1))) unsigned int*)(gp), \
    (__attribute__((address_space(3))) unsigned int*)(lp), 16, 0, 0)

// ---------------------------------------------------------------- W converts
// z=0: Wtt = Wt^T bf16; z=1: Wlt = Wl^T bf16; z=2: Wtb = Wt bf16 (no transpose)
__global__ void k_wcvt(const float* __restrict__ Wt, const float* __restrict__ Wl,
                       short* __restrict__ Wtt, short* __restrict__ Wlt,
                       short* __restrict__ Wtb) {
  __shared__ float tile[64][65];
  int z = blockIdx.z;
  int kb = blockIdx.x * 64;
  int nb = blockIdx.y * 64;
  int t = threadIdx.x;
  int c = t & 63;
  int r0 = (t >> 6) * 16;
  if (z == 2) {
#pragma unroll
    for (int i = 0; i < 16; ++i) {
      int r = kb + r0 + i;
      Wtb[(size_t)r * DD + nb + c] = f2bf(Wt[(size_t)r * DD + nb + c]);
    }
    return;
  }
  const float* src = z ? Wl : Wt;
  short* dst = z ? Wlt : Wtt;
#pragma unroll
  for (int i = 0; i < 16; ++i)
    tile[r0 + i][c] = src[(size_t)(kb + r0 + i) * DD + nb + c];
  __syncthreads();
#pragma unroll
  for (int i = 0; i < 16; ++i)
    dst[(size_t)(nb + r0 + i) * HH + kb + c] = f2bf(tile[c][r0 + i]);
}

// ---------------------------------------------------------------- hbar = segment-mean of hs
__global__ void k_hbar(const float* __restrict__ hs, const int* __restrict__ lmask,
                       float* __restrict__ hbar) {
  int b = blockIdx.x >> 3, m = blockIdx.x & 7;
  int t = threadIdx.x;
  int lane = t & 63, w = t >> 6;
  __shared__ int list[LL];
  __shared__ int nlist_s;
  if (w == 0) {  // deterministic compaction of matching token indices
    int base = 0;
    for (int win = 0; win < LL / 64; ++win) {
      int l = win * 64 + lane;
      bool match = (lmask[b * LL + l] == m + 1);
      unsigned long long mk = __ballot(match);
      if (match) {
        int pos = base + (int)__popcll(mk & ((1ull << lane) - 1ull));
        list[pos] = l;
      }
      base += (int)__popcll(mk);
    }
    if (lane == 0) nlist_s = base;
  }
  __syncthreads();
  int n = nlist_s;
  float inv = 1.0f / (float)(n > 1 ? n : 1);
  float a0 = 0.f, a1 = 0.f, a2 = 0.f;
  for (int i = 0; i < n; ++i) {
    const float* r = hs + (size_t)(b * LL + list[i]) * HH;
    a0 += r[t]; a1 += r[t + 256]; a2 += r[t + 512];
  }
  float* dst = hbar + (size_t)(b * MM + m) * HH;
  dst[t] = a0 * inv; dst[t + 256] = a1 * inv; dst[t + 512] = a2 * inv;
}

// ---------------------------------------------------------------- shared GEMM body (proven r6/r9)
#define Bb_M 128
#define Bb_N 128
#define Bb_K 64
#define NTK 12

struct GemmAcc { f32x4 acc[4][4]; };

__device__ __forceinline__ void gemm_body(
    short* AsB, short* BsB,
    const float* A, const short* Bt, int m0, int n0, int lda_k,
    GemmAcc& g, int t) {
  int lane = t & 63;
  int w = t >> 6;
  int wm = w >> 1, wn = w & 1;

  float4 areg[8];

  auto issueA = [&](int kt) {
    const float* Ag = A + (size_t)m0 * lda_k + kt * Bb_K;
#pragma unroll
    for (int i = 0; i < 8; ++i) {
      int slot = i * 256 + t;
      int row = slot >> 4, c = slot & 15;
      areg[i] = *(const float4*)(Ag + (size_t)row * lda_k + c * 4);
    }
  };
  auto issueB = [&](int kt, int buf) {
    const short* Bg = Bt + (size_t)n0 * lda_k + kt * Bb_K;
#pragma unroll
    for (int i = 0; i < 4; ++i) {
      int slot = i * 256 + w * 64 + lane;
      int row = slot >> 3, c = slot & 7;
      int cs = c ^ (row & 7);
      GLOAD_LDS16(Bg + (size_t)row * lda_k + cs * 8,
                  (char*)BsB + (size_t)buf * 16384 + (size_t)(i * 256 + w * 64) * 16);
    }
  };
  auto writeA = [&]() {
#pragma unroll
    for (int i = 0; i < 8; ++i) {
      int slot = i * 256 + t;
      int row = slot >> 4, c = slot & 15;
      unsigned d0, d1;
      asm("v_cvt_pk_bf16_f32 %0, %1, %2" : "=v"(d0) : "v"(areg[i].x), "v"(areg[i].y));
      asm("v_cvt_pk_bf16_f32 %0, %1, %2" : "=v"(d1) : "v"(areg[i].z), "v"(areg[i].w));
      int phys = (c >> 1) ^ (row & 7);
      uint2 val = {d0, d1};
      *(uint2*)((char*)AsB + (size_t)row * 128 + phys * 16 + (c & 1) * 8) = val;
    }
  };
  auto compute = [&](int buf) {
#pragma unroll
    for (int kk = 0; kk < 2; ++kk) {
      s16x8 a[4], bb[4];
#pragma unroll
      for (int i = 0; i < 4; ++i) {
        int row = wm * 64 + i * 16 + (lane & 15);
        int p = (kk * 4 + (lane >> 4)) ^ (row & 7);
        a[i] = *(const s16x8*)((const char*)AsB + (size_t)row * 128 + p * 16);
      }
#pragma unroll
      for (int i = 0; i < 4; ++i) {
        int row = wn * 64 + i * 16 + (lane & 15);
        int p = (kk * 4 + (lane >> 4)) ^ (row & 7);
        bb[i] = *(const s16x8*)((const char*)BsB + (size_t)buf * 16384 + (size_t)row * 128 + p * 16);
      }
#pragma unroll
      for (int mi = 0; mi < 4; ++mi)
#pragma unroll
        for (int ni = 0; ni < 4; ++ni)
          g.acc[mi][ni] = __builtin_amdgcn_mfma_f32_16x16x32_bf16(a[mi], bb[ni], g.acc[mi][ni], 0, 0, 0);
    }
  };

  issueA(0); issueB(0, 0);
  writeA();
  __syncthreads();
  for (int kt = 0; kt < NTK; ++kt) {
    if (kt + 1 < NTK) { issueA(kt + 1); issueB(kt + 1, (kt + 1) & 1); }
    compute(kt & 1);
    __syncthreads();
    if (kt + 1 < NTK) {
      writeA();
      __syncthreads();
    }
  }
}

// ---------------------------------------------------------------- agg = hbar @ Wl^T + bl -> out
__global__ __launch_bounds__(256, 3)
void k_gemm_agg(const float* __restrict__ hbar, const short* __restrict__ Wlt,
                const float* __restrict__ bl, float* __restrict__ out) {
  __shared__ short As[Bb_M][Bb_K];
  __shared__ short Bs[2][Bb_N][Bb_K];
  int t = threadIdx.x;
  int lane = t & 63, w = t >> 6;
  int wm = w >> 1, wn = w & 1;
  int n0 = blockIdx.x * Bb_N;

  GemmAcc g = {};
  gemm_body(&As[0][0], &Bs[0][0][0], hbar, Wlt, 0, n0, HH, g, t);

#pragma unroll
  for (int mi = 0; mi < 4; ++mi) {
    int row = wm * 64 + mi * 16 + ((lane >> 4) * 4);
#pragma unroll
    for (int ni = 0; ni < 4; ++ni) {
      int col = n0 + wn * 64 + ni * 16 + (lane & 15);
      float bv = bl[col];
#pragma unroll
      for (int j = 0; j < 4; ++j)
        out[O_AGGL + (size_t)(row + j) * DD + col] = g.acc[mi][ni][j] + bv;
    }
  }
}

// ---------------------------------------------------------------- qh = agg @ Wt^T ; cvec = agg . bt
__global__ __launch_bounds__(256, 3)
void k_qh(const float* __restrict__ out, const short* __restrict__ Wtb,
          const float* __restrict__ bt, float* __restrict__ qh, float* __restrict__ cvec) {
  const float* agg = out + O_AGGL;
  if (blockIdx.x == 6) {          // cvec block (no barriers)
    int t = threadIdx.x;
    if (t < 128) {
      float s = 0.f;
#pragma unroll 4
      for (int d = 0; d < DD; ++d) s += agg[(size_t)t * DD + d] * bt[d];
      cvec[t] = s;
    }
    return;
  }
  __shared__ short As[Bb_M][Bb_K];
  __shared__ short Bs[2][Bb_N][Bb_K];
  int t = threadIdx.x;
  int lane = t & 63, w = t >> 6;
  int wm = w >> 1, wn = w & 1;
  int n0 = blockIdx.x * Bb_N;

  GemmAcc g = {};
  gemm_body(&As[0][0], &Bs[0][0][0], agg, Wtb, 0, n0, DD, g, t);

#pragma unroll
  for (int mi = 0; mi < 4; ++mi) {
    int row = wm * 64 + mi * 16 + ((lane >> 4) * 4);
#pragma unroll
    for (int ni = 0; ni < 4; ++ni) {
      int col = n0 + wn * 64 + ni * 16 + (lane & 15);
#pragma unroll
      for (int j = 0; j < 4; ++j)
        qh[(size_t)(row + j) * HH + col] = g.acc[mi][ni][j];
    }
  }
}

// ---------------------------------------------------------------- scores via MFMA from hs
// S[tok][m] = hs[tok][:] . qh[m][:] + cvec[m], masked, /temp.
// A = hs fp32 reg-staged -> cvt_pk -> double-buffered swizzled bf16 LDS
// (one barrier per K-step: writeA targets the inactive buffer after compute).
// B = qh staged once as bf16 [16][776] padded LDS.
__global__ __launch_bounds__(256, 3)
void k_scores_mfma(const float* __restrict__ hs, const float* __restrict__ qh,
                   const float* __restrict__ cvec, const int* __restrict__ lmask,
                   const int* __restrict__ amask, const float* __restrict__ temp_p,
                   float* __restrict__ scores) {
  __shared__ short As[2][64][64];   // 16 KB
  __shared__ short Bs[16][776];     // 24.8 KB, +8 pad -> 2-way banks (free)
  int chunk = blockIdx.x;           // 32 chunks of 64 tokens
  int b = blockIdx.y;               // 16
  int t = threadIdx.x;
  int lane = t & 63, w = t >> 6;

  // stage qh (8 real rows) as bf16; zero rows 8..15
  const float* qsrc = qh + (size_t)b * MM * HH;
  for (int c = t; c < HH; c += 256) {
#pragma unroll
    for (int r = 0; r < 8; ++r) Bs[r][c] = f2bf(qsrc[(size_t)r * HH + c]);
#pragma unroll
    for (int r = 8; r < 16; ++r) Bs[r][c] = 0;
  }

  const float* Hg = hs + (size_t)(b * LL + chunk * 64) * HH;
  float4 areg[4];
  auto issueA = [&](int kt) {
#pragma unroll
    for (int i = 0; i < 4; ++i) {
      int slot = i * 256 + t;                 // 1024 fp32 quads (64 rows x 16)
      int row = slot >> 4, c = slot & 15;
      areg[i] = *(const float4*)(Hg + (size_t)row * HH + kt * 64 + c * 4);
    }
  };
  auto writeA = [&](int buf) {
#pragma unroll
    for (int i = 0; i < 4; ++i) {
      int slot = i * 256 + t;
      int row = slot >> 4, c = slot & 15;     // c = 8B-unit index of bf16 row
      unsigned d0, d1;
      asm("v_cvt_pk_bf16_f32 %0, %1, %2" : "=v"(d0) : "v"(areg[i].x), "v"(areg[i].y));
      asm("v_cvt_pk_bf16_f32 %0, %1, %2" : "=v"(d1) : "v"(areg[i].z), "v"(areg[i].w));
      int phys = (c >> 1) ^ (row & 7);
      uint2 val = {d0, d1};
      *(uint2*)((char*)&As[buf][0][0] + (size_t)row * 128 + phys * 16 + (c & 1) * 8) = val;
    }
  };

  f32x4 acc = {};
  issueA(0);
  writeA(0);
  __syncthreads();                  // Bs + As(0) committed
  for (int kt = 0; kt < 12; ++kt) {
    if (kt + 1 < 12) issueA(kt + 1);
    int buf = kt & 1;
#pragma unroll
    for (int kk = 0; kk < 2; ++kk) {
      int arow = w * 16 + (lane & 15);
      int p = (kk * 4 + (lane >> 4)) ^ (arow & 7);
      s16x8 a = *(const s16x8*)((const char*)&As[buf][0][0] + (size_t)arow * 128 + p * 16);
      s16x8 bfr = *(const s16x8*)&Bs[lane & 15][kt * 64 + kk * 32 + (lane >> 4) * 8];
      acc = __builtin_amdgcn_mfma_f32_16x16x32_bf16(a, bfr, acc, 0, 0, 0);
    }
    if (kt + 1 < 12) writeA(buf ^ 1);   // inactive buffer; safe pre-barrier
    __syncthreads();                    // As(kt+1) visible for next iteration
  }

  float inv_temp = 1.0f / fmaxf(fabsf(temp_p[0]), 0.1f);
  int m = lane & 15;
  int tok0 = chunk * 64 + w * 16 + (lane >> 4) * 4;
  if (m < MM) {
    float cv = cvec[b * MM + m];
    int4 lm = *(const int4*)&lmask[b * LL + tok0];
    int4 am = *(const int4*)&amask[b * LL + tok0];
    float4 o;
    o.x = (lm.x == 0 && am.x == 1) ? (acc[0] + cv) * inv_temp : -1e30f;
    o.y = (lm.y == 0 && am.y == 1) ? (acc[1] + cv) * inv_temp : -1e30f;
    o.z = (lm.z == 0 && am.z == 1) ? (acc[2] + cv) * inv_temp : -1e30f;
    o.w = (lm.w == 0 && am.w == 1) ? (acc[3] + cv) * inv_temp : -1e30f;
    *(float4*)&scores[(size_t)(b * MM + m) * LL + tok0] = o;
  }
}

// ---------------------------------------------------------------- row softmax (in place)
__global__ void k_softmax(float* __restrict__ scores) {
  int row = blockIdx.x;
  float* s = scores + (size_t)row * LL;
  int t = threadIdx.x;
  int w = t >> 6, lane = t & 63;
  float v[8];
  float mx = -1e30f;
#pragma unroll
  for (int i = 0; i < 8; ++i) { v[i] = s[t + 256 * i]; mx = fmaxf(mx, v[i]); }
  for (int sh = 32; sh; sh >>= 1) mx = fmaxf(mx, __shfl_xor(mx, sh, 64));
  __shared__ float wred[4];
  __shared__ float wsum[4];
  if (lane == 0) wred[w] = mx;
  __syncthreads();
  mx = fmaxf(fmaxf(wred[0], wred[1]), fmaxf(wred[2], wred[3]));
  float sum = 0.f;
#pragma unroll
  for (int i = 0; i < 8; ++i) { v[i] = __expf(v[i] - mx); sum += v[i]; }
  for (int sh = 32; sh; sh >>= 1) sum += __shfl_xor(sum, sh, 64);
  if (lane == 0) wsum[w] = sum;
  __syncthreads();
  sum = wsum[0] + wsum[1] + wsum[2] + wsum[3];
  float inv = 1.0f / sum;
#pragma unroll
  for (int i = 0; i < 8; ++i) s[t + 256 * i] = v[i] * inv;
}

// ---------------------------------------------------------------- hst partials = attn-pool of hs
__global__ void k_pool(const float* __restrict__ hs, const float* __restrict__ attn,
                       float* __restrict__ part) {
  int lc = blockIdx.x;   // 8 chunks of 256 tokens
  int ht = blockIdx.y;   // 6 tiles of 128 h
  int b  = blockIdx.z;   // 16
  int t = threadIdx.x;
  int m  = t >> 5;
  int c4 = t & 31;
  __shared__ float at_l[MM][256];
  for (int i = t; i < MM * 256; i += 256) {
    int mm = i >> 8, ll = i & 255;
    at_l[mm][ll] = attn[(size_t)(b * MM + mm) * LL + lc * 256 + ll];
  }
  __syncthreads();
  float ax = 0.f, ay = 0.f, az = 0.f, aw = 0.f;
  const float* p = hs + (size_t)(b * LL + lc * 256) * HH + ht * 128 + c4 * 4;
#pragma unroll 4
  for (int ll = 0; ll < 256; ++ll) {
    float4 hv = *(const float4*)(p + (size_t)ll * HH);
    float a = at_l[m][ll];
    ax += a * hv.x; ay += a * hv.y; az += a * hv.z; aw += a * hv.w;
  }
  float4 acc = {ax, ay, az, aw};
  *(float4*)&part[((size_t)(lc * BB + b) * MM + m) * HH + ht * 128 + c4 * 4] = acc;
}

// ---------------------------------------------------------------- hst = sum of partials
__global__ void k_sumhst(const float* __restrict__ part, float* __restrict__ hst) {
  int idx4 = blockIdx.x * 256 + threadIdx.x;   // 24576 float4
  float4 s = {0.f, 0.f, 0.f, 0.f};
#pragma unroll
  for (int lc = 0; lc < 8; ++lc) {
    float4 v = *(const float4*)&part[(size_t)lc * 98304 + (size_t)idx4 * 4];
    s.x += v.x; s.y += v.y; s.z += v.z; s.w += v.w;
  }
  *(float4*)&hst[(size_t)idx4 * 4] = s;
}

// ---------------------------------------------------------------- aggregated_text = hst @ Wt + bt -> out
__global__ __launch_bounds__(256, 3)
void k_aggt(const float* __restrict__ hst, const short* __restrict__ Wtt,
            const float* __restrict__ bt, float* __restrict__ out) {
  __shared__ short As[Bb_M][Bb_K];
  __shared__ short Bs[2][Bb_N][Bb_K];
  int t = threadIdx.x;
  int lane = t & 63, w = t >> 6;
  int wm = w >> 1, wn = w & 1;
  int n0 = blockIdx.x * Bb_N;

  GemmAcc g = {};
  gemm_body(&As[0][0], &Bs[0][0][0], hst, Wtt, 0, n0, HH, g, t);

#pragma unroll
  for (int mi = 0; mi < 4; ++mi) {
    int row = wm * 64 + mi * 16 + ((lane >> 4) * 4);
#pragma unroll
    for (int ni = 0; ni < 4; ++ni) {
      int col = n0 + wn * 64 + ni * 16 + (lane & 15);
      float bv = bt[col];
#pragma unroll
      for (int j = 0; j < 4; ++j)
        out[O_AGGT + (size_t)(row + j) * DD + col] = g.acc[mi][ni][j] + bv;
    }
  }
}

// ---------------------------------------------------------------- cosine head + ids + scale
__global__ void k_head(const float* __restrict__ lscale_p, float* __restrict__ out) {
  int row = blockIdx.x;   // 128
  int lane = threadIdx.x; // 64
  const float* at = out + O_AGGT + (size_t)row * DD;
  const float* al = out + O_AGGL + (size_t)row * DD;
  float dot = 0.f, nt = 0.f, nl = 0.f;
  for (int i = lane; i < DD; i += 64) {
    float a = at[i], c = al[i];
    dot += a * c; nt += a * a; nl += c * c;
  }
  for (int s = 32; s; s >>= 1) {
    dot += __shfl_xor(dot, s, 64);
    nt  += __shfl_xor(nt, s, 64);
    nl  += __shfl_xor(nl, s, 64);
  }
  if (lane == 0) {
    float scale = expf(lscale_p[0]);
    float denom = fmaxf(sqrtf(nt), 1e-8f) * fmaxf(sqrtf(nl), 1e-8f);
    out[O_LOGITS + row] = dot / denom * scale;
    out[O_BID + row] = (float)(row >> 3);
    out[O_LID + row] = (float)((row & 7) + 1);
    if (row == 0) out[O_SCALE] = scale;
  }
}

extern "C" void kernel_launch(void* const* d_in, const int* in_sizes, int n_in,
                              void* d_out, int out_size, void* d_ws, size_t ws_size,
                              hipStream_t stream) {
  const float* hs    = (const float*)d_in[0];
  const float* Wt    = (const float*)d_in[1];
  const float* bt    = (const float*)d_in[2];
  const float* Wl    = (const float*)d_in[3];
  const float* bl    = (const float*)d_in[4];
  const float* atemp = (const float*)d_in[5];
  const float* lsc   = (const float*)d_in[6];
  const int*   lmask = (const int*)d_in[7];
  const int*   amask = (const int*)d_in[9];
  float* out = (float*)d_out;
  char* ws = (char*)d_ws;
  short* Wtt  = (short*)(ws + WTT_OFF);
  short* Wlt  = (short*)(ws + WLT_OFF);
  short* Wtb  = (short*)(ws + WTB_OFF);
  float* hbar = (float*)(ws + HBAR_OFF);
  float* qh   = (float*)(ws + QH_OFF);
  float* hst  = (float*)(ws + HST_OFF);
  float* cvec = (float*)(ws + CVEC_OFF);
  float* scores = (float*)(ws + SC_OFF);
  float* part   = (float*)(ws + PART_OFF);

  k_wcvt<<<dim3(12, 12, 3), 256, 0, stream>>>(Wt, Wl, Wtt, Wlt, Wtb);
  k_hbar<<<128, 256, 0, stream>>>(hs, lmask, hbar);
  k_gemm_agg<<<6, 256, 0, stream>>>(hbar, Wlt, bl, out);
  k_qh<<<7, 256, 0, stream>>>(out, Wtb, bt, qh, cvec);
  k_scores_mfma<<<dim3(32, 16), 256, 0, stream>>>(hs, qh, cvec, lmask, amask, atemp, scores);
  k_softmax<<<128, 256, 0, stream>>>(scores);
  k_pool<<<dim3(8, 6, 16), 256, 0, stream>>>(hs, scores, part);
  k_sumhst<<<96, 256, 0, stream>>>(part, hst);
  k_aggt<<<6, 256, 0, stream>>>(hst, Wtt, bt, out);
  k_head<<<128, 64, 0, stream>>>(lsc, out);
}

// Round 12
// 131.038 us; speedup vs baseline: 1.2647x; 1.0882x over previous
//
#include <hip/hip_runtime.h>
#include <hip/hip_bf16.h>

typedef __attribute__((ext_vector_type(8))) short s16x8;
typedef __attribute__((ext_vector_type(4))) float f32x4;

#define BB 16
#define LL 2048
#define HH 768
#define DD 768
#define MM 8

// d_out layout (float elements)
#define O_LOGITS 0
#define O_BID    128
#define O_LID    256
#define O_AGGL   384
#define O_SCALE  98688
#define O_AGGT   98689

// ws layout (bytes)
#define WTT_OFF  0u          // Wt^T bf16 768*768*2
#define WLT_OFF  1179648u    // Wl^T bf16
#define WTB_OFF  2359296u    // Wt bf16 (natural)
#define HBAR_OFF 3538944u    // 128*768 fp32
#define QH_OFF   3932160u    // 128*768 fp32
#define HST_OFF  4325376u    // 128*768 fp32
#define CVEC_OFF 4718592u    // 128 fp32
#define PML_OFF  4719104u    // 32*16*8*2 fp32 = 32768
#define PO_OFF   4751872u    // 32*16*8*768 fp32 = 12582912

__device__ __forceinline__ short f2bf(float x) {
  union { float f; unsigned u; } v; v.f = x;
  unsigned r = v.u + 0x7FFFu + ((v.u >> 16) & 1u);
  return (short)(r >> 16);
}

// async global->LDS, 16B per lane; LDS dest is wave-uniform base (HW adds lane*16)
#define GLOAD_LDS16(gp, lp) __builtin_amdgcn_global_load_lds( \
    (const __attribute__((address_space(1))) unsigned int*)(gp), \
    (__attribute__((address_space(3))) unsigned int*)(lp), 16, 0, 0)

// ---------------------------------------------------------------- W converts
__global__ void k_wcvt(const float* __restrict__ Wt, const float* __restrict__ Wl,
                       short* __restrict__ Wtt, short* __restrict__ Wlt,
                       short* __restrict__ Wtb) {
  __shared__ float tile[64][65];
  int z = blockIdx.z;
  int kb = blockIdx.x * 64;
  int nb = blockIdx.y * 64;
  int t = threadIdx.x;
  int c = t & 63;
  int r0 = (t >> 6) * 16;
  if (z == 2) {
#pragma unroll
    for (int i = 0; i < 16; ++i) {
      int r = kb + r0 + i;
      Wtb[(size_t)r * DD + nb + c] = f2bf(Wt[(size_t)r * DD + nb + c]);
    }
    return;
  }
  const float* src = z ? Wl : Wt;
  short* dst = z ? Wlt : Wtt;
#pragma unroll
  for (int i = 0; i < 16; ++i)
    tile[r0 + i][c] = src[(size_t)(kb + r0 + i) * DD + nb + c];
  __syncthreads();
#pragma unroll
  for (int i = 0; i < 16; ++i)
    dst[(size_t)(nb + r0 + i) * HH + kb + c] = f2bf(tile[c][r0 + i]);
}

// ---------------------------------------------------------------- hbar = segment-mean of hs
__global__ void k_hbar(const float* __restrict__ hs, const int* __restrict__ lmask,
                       float* __restrict__ hbar) {
  int b = blockIdx.x >> 3, m = blockIdx.x & 7;
  int t = threadIdx.x;
  int lane = t & 63, w = t >> 6;
  __shared__ int list[LL];
  __shared__ int nlist_s;
  if (w == 0) {
    int base = 0;
    for (int win = 0; win < LL / 64; ++win) {
      int l = win * 64 + lane;
      bool match = (lmask[b * LL + l] == m + 1);
      unsigned long long mk = __ballot(match);
      if (match) {
        int pos = base + (int)__popcll(mk & ((1ull << lane) - 1ull));
        list[pos] = l;
      }
      base += (int)__popcll(mk);
    }
    if (lane == 0) nlist_s = base;
  }
  __syncthreads();
  int n = nlist_s;
  float inv = 1.0f / (float)(n > 1 ? n : 1);
  float a0 = 0.f, a1 = 0.f, a2 = 0.f;
  for (int i = 0; i < n; ++i) {
    const float* r = hs + (size_t)(b * LL + list[i]) * HH;
    a0 += r[t]; a1 += r[t + 256]; a2 += r[t + 512];
  }
  float* dst = hbar + (size_t)(b * MM + m) * HH;
  dst[t] = a0 * inv; dst[t + 256] = a1 * inv; dst[t + 512] = a2 * inv;
}

// ---------------------------------------------------------------- shared GEMM body (proven r6/r9)
#define Bb_M 128
#define Bb_N 128
#define Bb_K 64
#define NTK 12

struct GemmAcc { f32x4 acc[4][4]; };

__device__ __forceinline__ void gemm_body(
    short* AsB, short* BsB,
    const float* A, const short* Bt, int m0, int n0, int lda_k,
    GemmAcc& g, int t) {
  int lane = t & 63;
  int w = t >> 6;
  int wm = w >> 1, wn = w & 1;

  float4 areg[8];

  auto issueA = [&](int kt) {
    const float* Ag = A + (size_t)m0 * lda_k + kt * Bb_K;
#pragma unroll
    for (int i = 0; i < 8; ++i) {
      int slot = i * 256 + t;
      int row = slot >> 4, c = slot & 15;
      areg[i] = *(const float4*)(Ag + (size_t)row * lda_k + c * 4);
    }
  };
  auto issueB = [&](int kt, int buf) {
    const short* Bg = Bt + (size_t)n0 * lda_k + kt * Bb_K;
#pragma unroll
    for (int i = 0; i < 4; ++i) {
      int slot = i * 256 + w * 64 + lane;
      int row = slot >> 3, c = slot & 7;
      int cs = c ^ (row & 7);
      GLOAD_LDS16(Bg + (size_t)row * lda_k + cs * 8,
                  (char*)BsB + (size_t)buf * 16384 + (size_t)(i * 256 + w * 64) * 16);
    }
  };
  auto writeA = [&]() {
#pragma unroll
    for (int i = 0; i < 8; ++i) {
      int slot = i * 256 + t;
      int row = slot >> 4, c = slot & 15;
      unsigned d0, d1;
      asm("v_cvt_pk_bf16_f32 %0, %1, %2" : "=v"(d0) : "v"(areg[i].x), "v"(areg[i].y));
      asm("v_cvt_pk_bf16_f32 %0, %1, %2" : "=v"(d1) : "v"(areg[i].z), "v"(areg[i].w));
      int phys = (c >> 1) ^ (row & 7);
      uint2 val = {d0, d1};
      *(uint2*)((char*)AsB + (size_t)row * 128 + phys * 16 + (c & 1) * 8) = val;
    }
  };
  auto compute = [&](int buf) {
#pragma unroll
    for (int kk = 0; kk < 2; ++kk) {
      s16x8 a[4], bb[4];
#pragma unroll
      for (int i = 0; i < 4; ++i) {
        int row = wm * 64 + i * 16 + (lane & 15);
        int p = (kk * 4 + (lane >> 4)) ^ (row & 7);
        a[i] = *(const s16x8*)((const char*)AsB + (size_t)row * 128 + p * 16);
      }
#pragma unroll
      for (int i = 0; i < 4; ++i) {
        int row = wn * 64 + i * 16 + (lane & 15);
        int p = (kk * 4 + (lane >> 4)) ^ (row & 7);
        bb[i] = *(const s16x8*)((const char*)BsB + (size_t)buf * 16384 + (size_t)row * 128 + p * 16);
      }
#pragma unroll
      for (int mi = 0; mi < 4; ++mi)
#pragma unroll
        for (int ni = 0; ni < 4; ++ni)
          g.acc[mi][ni] = __builtin_amdgcn_mfma_f32_16x16x32_bf16(a[mi], bb[ni], g.acc[mi][ni], 0, 0, 0);
    }
  };

  issueA(0); issueB(0, 0);
  writeA();
  __syncthreads();
  for (int kt = 0; kt < NTK; ++kt) {
    if (kt + 1 < NTK) { issueA(kt + 1); issueB(kt + 1, (kt + 1) & 1); }
    compute(kt & 1);
    __syncthreads();
    if (kt + 1 < NTK) {
      writeA();
      __syncthreads();
    }
  }
}

// ---------------------------------------------------------------- agg = hbar @ Wl^T + bl -> out
__global__ __launch_bounds__(256, 3)
void k_gemm_agg(const float* __restrict__ hbar, const short* __restrict__ Wlt,
                const float* __restrict__ bl, float* __restrict__ out) {
  __shared__ short As[Bb_M][Bb_K];
  __shared__ short Bs[2][Bb_N][Bb_K];
  int t = threadIdx.x;
  int lane = t & 63, w = t >> 6;
  int wm = w >> 1, wn = w & 1;
  int n0 = blockIdx.x * Bb_N;

  GemmAcc g = {};
  gemm_body(&As[0][0], &Bs[0][0][0], hbar, Wlt, 0, n0, HH, g, t);

#pragma unroll
  for (int mi = 0; mi < 4; ++mi) {
    int row = wm * 64 + mi * 16 + ((lane >> 4) * 4);
#pragma unroll
    for (int ni = 0; ni < 4; ++ni) {
      int col = n0 + wn * 64 + ni * 16 + (lane & 15);
      float bv = bl[col];
#pragma unroll
      for (int j = 0; j < 4; ++j)
        out[O_AGGL + (size_t)(row + j) * DD + col] = g.acc[mi][ni][j] + bv;
    }
  }
}

// ---------------------------------------------------------------- qh = agg @ Wt^T ; cvec = agg . bt
__global__ __launch_bounds__(256, 3)
void k_qh(const float* __restrict__ out, const short* __restrict__ Wtb,
          const float* __restrict__ bt, float* __restrict__ qh, float* __restrict__ cvec) {
  const float* agg = out + O_AGGL;
  if (blockIdx.x == 6) {
    int t = threadIdx.x;
    if (t < 128) {
      float s = 0.f;
#pragma unroll 4
      for (int d = 0; d < DD; ++d) s += agg[(size_t)t * DD + d] * bt[d];
      cvec[t] = s;
    }
    return;
  }
  __shared__ short As[Bb_M][Bb_K];
  __shared__ short Bs[2][Bb_N][Bb_K];
  int t = threadIdx.x;
  int lane = t & 63, w = t >> 6;
  int wm = w >> 1, wn = w & 1;
  int n0 = blockIdx.x * Bb_N;

  GemmAcc g = {};
  gemm_body(&As[0][0], &Bs[0][0][0], agg, Wtb, 0, n0, DD, g, t);

#pragma unroll
  for (int mi = 0; mi < 4; ++mi) {
    int row = wm * 64 + mi * 16 + ((lane >> 4) * 4);
#pragma unroll
    for (int ni = 0; ni < 4; ++ni) {
      int col = n0 + wn * 64 + ni * 16 + (lane & 15);
#pragma unroll
      for (int j = 0; j < 4; ++j)
        qh[(size_t)(row + j) * HH + col] = g.acc[mi][ni][j];
    }
  }
}

// ---------------------------------------------------------------- fused scores+softmax-partial+pool
// Phase 1: S[64 tok][m] = hs.qh + cvec via MFMA (proven r11 structure), s -> LDS.
// Phase 2: per-m chunk-local max/expsum (one token per lane); w = exp(s - m_loc).
// Phase 3: partial pool o[m][h] = sum_tok w * hs[tok][h] (fp32 re-read, L2-hot).
// Fully-masked chunks need no guard: finish's exp(m_loc - m_glob) factor -> 0.
__global__ __launch_bounds__(256, 3)
void k_attnpool(const float* __restrict__ hs, const float* __restrict__ qh,
                const float* __restrict__ cvec, const int* __restrict__ lmask,
                const int* __restrict__ amask, const float* __restrict__ temp_p,
                float* __restrict__ part_o, float* __restrict__ part_ml) {
  __shared__ short As[2][64][64];   // 16 KB
  __shared__ short Bs[16][776];     // 24.8 KB
  __shared__ float w_lds[64][8];    // 2 KB: s, then w
  int chunk = blockIdx.x;           // 32 chunks of 64 tokens
  int b = blockIdx.y;               // 16
  int t = threadIdx.x;
  int lane = t & 63, w = t >> 6;

  // stage qh (8 real rows) as bf16; zero rows 8..15
  const float* qsrc = qh + (size_t)b * MM * HH;
  for (int c = t; c < HH; c += 256) {
#pragma unroll
    for (int r = 0; r < 8; ++r) Bs[r][c] = f2bf(qsrc[(size_t)r * HH + c]);
#pragma unroll
    for (int r = 8; r < 16; ++r) Bs[r][c] = 0;
  }

  const float* Hg = hs + (size_t)(b * LL + chunk * 64) * HH;
  float4 areg[4];
  auto issueA = [&](int kt) {
#pragma unroll
    for (int i = 0; i < 4; ++i) {
      int slot = i * 256 + t;
      int row = slot >> 4, c = slot & 15;
      areg[i] = *(const float4*)(Hg + (size_t)row * HH + kt * 64 + c * 4);
    }
  };
  auto writeA = [&](int buf) {
#pragma unroll
    for (int i = 0; i < 4; ++i) {
      int slot = i * 256 + t;
      int row = slot >> 4, c = slot & 15;
      unsigned d0, d1;
      asm("v_cvt_pk_bf16_f32 %0, %1, %2" : "=v"(d0) : "v"(areg[i].x), "v"(areg[i].y));
      asm("v_cvt_pk_bf16_f32 %0, %1, %2" : "=v"(d1) : "v"(areg[i].z), "v"(areg[i].w));
      int phys = (c >> 1) ^ (row & 7);
      uint2 val = {d0, d1};
      *(uint2*)((char*)&As[buf][0][0] + (size_t)row * 128 + phys * 16 + (c & 1) * 8) = val;
    }
  };

  f32x4 acc = {};
  issueA(0);
  writeA(0);
  __syncthreads();
  for (int kt = 0; kt < 12; ++kt) {
    if (kt + 1 < 12) issueA(kt + 1);
    int buf = kt & 1;
#pragma unroll
    for (int kk = 0; kk < 2; ++kk) {
      int arow = w * 16 + (lane & 15);
      int p = (kk * 4 + (lane >> 4)) ^ (arow & 7);
      s16x8 a = *(const s16x8*)((const char*)&As[buf][0][0] + (size_t)arow * 128 + p * 16);
      s16x8 bfr = *(const s16x8*)&Bs[lane & 15][kt * 64 + kk * 32 + (lane >> 4) * 8];
      acc = __builtin_amdgcn_mfma_f32_16x16x32_bf16(a, bfr, acc, 0, 0, 0);
    }
    if (kt + 1 < 12) writeA(buf ^ 1);
    __syncthreads();
  }

  // epilogue -> s in LDS
  float inv_temp = 1.0f / fmaxf(fabsf(temp_p[0]), 0.1f);
  int m = lane & 15;
  int tok0 = w * 16 + (lane >> 4) * 4;          // local token base
  if (m < MM) {
    float cv = cvec[b * MM + m];
    int4 lm = *(const int4*)&lmask[b * LL + chunk * 64 + tok0];
    int4 am = *(const int4*)&amask[b * LL + chunk * 64 + tok0];
    w_lds[tok0 + 0][m] = (lm.x == 0 && am.x == 1) ? (acc[0] + cv) * inv_temp : -1e30f;
    w_lds[tok0 + 1][m] = (lm.y == 0 && am.y == 1) ? (acc[1] + cv) * inv_temp : -1e30f;
    w_lds[tok0 + 2][m] = (lm.z == 0 && am.z == 1) ? (acc[2] + cv) * inv_temp : -1e30f;
    w_lds[tok0 + 3][m] = (lm.w == 0 && am.w == 1) ? (acc[3] + cv) * inv_temp : -1e30f;
  }
  __syncthreads();

  // Phase 2: wave w handles m = w and m = w+4 (one token per lane)
#pragma unroll
  for (int half = 0; half < 2; ++half) {
    int mm = w + half * 4;
    float v = w_lds[lane][mm];
    float mx = v;
    for (int s = 32; s; s >>= 1) mx = fmaxf(mx, __shfl_xor(mx, s, 64));
    float e = __expf(v - mx);
    float l = e;
    for (int s = 32; s; s >>= 1) l += __shfl_xor(l, s, 64);
    w_lds[lane][mm] = e;
    if (lane == 0) {
      float* pml = part_ml + ((size_t)(chunk * BB + b) * MM + mm) * 2;
      pml[0] = mx; pml[1] = l;
    }
  }
  __syncthreads();

  // Phase 3: partial pool; threads 0..191 own 4 h-cols each
  if (t < 192) {
    int h0 = t * 4;
    f32x4 o[8] = {};
    const float* hp = Hg + h0;
    for (int tok = 0; tok < 64; ++tok) {
      float4 hv = *(const float4*)(hp + (size_t)tok * HH);
      float4 w0 = *(const float4*)&w_lds[tok][0];
      float4 w1 = *(const float4*)&w_lds[tok][4];
      o[0][0] += w0.x * hv.x; o[0][1] += w0.x * hv.y; o[0][2] += w0.x * hv.z; o[0][3] += w0.x * hv.w;
      o[1][0] += w0.y * hv.x; o[1][1] += w0.y * hv.y; o[1][2] += w0.y * hv.z; o[1][3] += w0.y * hv.w;
      o[2][0] += w0.z * hv.x; o[2][1] += w0.z * hv.y; o[2][2] += w0.z * hv.z; o[2][3] += w0.z * hv.w;
      o[3][0] += w0.w * hv.x; o[3][1] += w0.w * hv.y; o[3][2] += w0.w * hv.z; o[3][3] += w0.w * hv.w;
      o[4][0] += w1.x * hv.x; o[4][1] += w1.x * hv.y; o[4][2] += w1.x * hv.z; o[4][3] += w1.x * hv.w;
      o[5][0] += w1.y * hv.x; o[5][1] += w1.y * hv.y; o[5][2] += w1.y * hv.z; o[5][3] += w1.y * hv.w;
      o[6][0] += w1.z * hv.x; o[6][1] += w1.z * hv.y; o[6][2] += w1.z * hv.z; o[6][3] += w1.z * hv.w;
      o[7][0] += w1.w * hv.x; o[7][1] += w1.w * hv.y; o[7][2] += w1.w * hv.z; o[7][3] += w1.w * hv.w;
    }
    float* po = part_o + (size_t)(chunk * BB + b) * MM * HH + h0;
#pragma unroll
    for (int mm = 0; mm < 8; ++mm)
      *(f32x4*)(po + (size_t)mm * HH) = o[mm];
  }
}

// ---------------------------------------------------------------- finish: flash-reduce partials -> hst
__global__ void k_finish(const float* __restrict__ part_o, const float* __restrict__ part_ml,
                         float* __restrict__ hst) {
  int row = blockIdx.x;    // 128 = b*8+m
  int b = row >> 3, m = row & 7;
  int t = threadIdx.x;     // 192
  float mg = -1e30f;
#pragma unroll
  for (int lc = 0; lc < 32; ++lc)
    mg = fmaxf(mg, part_ml[((size_t)(lc * BB + b) * MM + m) * 2]);
  float L = 0.f;
  f32x4 acc = {};
  int h0 = t * 4;
  for (int lc = 0; lc < 32; ++lc) {
    const float* pml = part_ml + ((size_t)(lc * BB + b) * MM + m) * 2;
    float f = __expf(pml[0] - mg);
    L += pml[1] * f;
    f32x4 v = *(const f32x4*)(part_o + ((size_t)(lc * BB + b) * MM + m) * HH + h0);
    acc[0] += v[0] * f; acc[1] += v[1] * f; acc[2] += v[2] * f; acc[3] += v[3] * f;
  }
  float inv = 1.0f / L;
  f32x4 r = {acc[0] * inv, acc[1] * inv, acc[2] * inv, acc[3] * inv};
  *(f32x4*)(hst + (size_t)row * HH + h0) = r;
}

// ---------------------------------------------------------------- aggregated_text = hst @ Wt + bt -> out
__global__ __launch_bounds__(256, 3)
void k_aggt(const float* __restrict__ hst, const short* __restrict__ Wtt,
            const float* __restrict__ bt, float* __restrict__ out) {
  __shared__ short As[Bb_M][Bb_K];
  __shared__ short Bs[2][Bb_N][Bb_K];
  int t = threadIdx.x;
  int lane = t & 63, w = t >> 6;
  int wm = w >> 1, wn = w & 1;
  int n0 = blockIdx.x * Bb_N;

  GemmAcc g = {};
  gemm_body(&As[0][0], &Bs[0][0][0], hst, Wtt, 0, n0, HH, g, t);

#pragma unroll
  for (int mi = 0; mi < 4; ++mi) {
    int row = wm * 64 + mi * 16 + ((lane >> 4) * 4);
#pragma unroll
    for (int ni = 0; ni < 4; ++ni) {
      int col = n0 + wn * 64 + ni * 16 + (lane & 15);
      float bv = bt[col];
#pragma unroll
      for (int j = 0; j < 4; ++j)
        out[O_AGGT + (size_t)(row + j) * DD + col] = g.acc[mi][ni][j] + bv;
    }
  }
}

// ---------------------------------------------------------------- cosine head + ids + scale
__global__ void k_head(const float* __restrict__ lscale_p, float* __restrict__ out) {
  int row = blockIdx.x;
  int lane = threadIdx.x;
  const float* at = out + O_AGGT + (size_t)row * DD;
  const float* al = out + O_AGGL + (size_t)row * DD;
  float dot = 0.f, nt = 0.f, nl = 0.f;
  for (int i = lane; i < DD; i += 64) {
    float a = at[i], c = al[i];
    dot += a * c; nt += a * a; nl += c * c;
  }
  for (int s = 32; s; s >>= 1) {
    dot += __shfl_xor(dot, s, 64);
    nt  += __shfl_xor(nt, s, 64);
    nl  += __shfl_xor(nl, s, 64);
  }
  if (lane == 0) {
    float scale = expf(lscale_p[0]);
    float denom = fmaxf(sqrtf(nt), 1e-8f) * fmaxf(sqrtf(nl), 1e-8f);
    out[O_LOGITS + row] = dot / denom * scale;
    out[O_BID + row] = (float)(row >> 3);
    out[O_LID + row] = (float)((row & 7) + 1);
    if (row == 0) out[O_SCALE] = scale;
  }
}

extern "C" void kernel_launch(void* const* d_in, const int* in_sizes, int n_in,
                              void* d_out, int out_size, void* d_ws, size_t ws_size,
                              hipStream_t stream) {
  const float* hs    = (const float*)d_in[0];
  const float* Wt    = (const float*)d_in[1];
  const float* bt    = (const float*)d_in[2];
  const float* Wl    = (const float*)d_in[3];
  const float* bl    = (const float*)d_in[4];
  const float* atemp = (const float*)d_in[5];
  const float* lsc   = (const float*)d_in[6];
  const int*   lmask = (const int*)d_in[7];
  const int*   amask = (const int*)d_in[9];
  float* out = (float*)d_out;
  char* ws = (char*)d_ws;
  short* Wtt  = (short*)(ws + WTT_OFF);
  short* Wlt  = (short*)(ws + WLT_OFF);
  short* Wtb  = (short*)(ws + WTB_OFF);
  float* hbar = (float*)(ws + HBAR_OFF);
  float* qh   = (float*)(ws + QH_OFF);
  float* hst  = (float*)(ws + HST_OFF);
  float* cvec = (float*)(ws + CVEC_OFF);
  float* pml  = (float*)(ws + PML_OFF);
  float* po   = (float*)(ws + PO_OFF);

  k_wcvt<<<dim3(12, 12, 3), 256, 0, stream>>>(Wt, Wl, Wtt, Wlt, Wtb);
  k_hbar<<<128, 256, 0, stream>>>(hs, lmask, hbar);
  k_gemm_agg<<<6, 256, 0, stream>>>(hbar, Wlt, bl, out);
  k_qh<<<7, 256, 0, stream>>>(out, Wtb, bt, qh, cvec);
  k_attnpool<<<dim3(32, 16), 256, 0, stream>>>(hs, qh, cvec, lmask, amask, atemp, po, pml);
  k_finish<<<128, 192, 0, stream>>>(po, pml, hst);
  k_aggt<<<6, 256, 0, stream>>>(hst, Wtt, bt, out);
  k_head<<<128, 64, 0, stream>>>(lsc, out);
}

// Round 13
// 87.924 us; speedup vs baseline: 1.8848x; 1.4904x over previous
//
#include <hip/hip_runtime.h>
#include <hip/hip_bf16.h>

typedef __attribute__((ext_vector_type(8))) short s16x8;
typedef __attribute__((ext_vector_type(4))) float f32x4;

#define BB 16
#define LL 2048
#define HH 768
#define DD 768
#define MM 8

// d_out layout (float elements)
#define O_LOGITS 0
#define O_BID    128
#define O_LID    256
#define O_AGGL   384
#define O_SCALE  98688
#define O_AGGT   98689

// ws layout (bytes)
#define WTT_OFF  0u          // Wt^T bf16 768*768*2
#define WLT_OFF  1179648u    // Wl^T bf16
#define WTB_OFF  2359296u    // Wt bf16 (natural)
#define HBAR_OFF 3538944u    // 128*768 fp32
#define QH_OFF   3932160u    // 128*768 fp32
#define HST_OFF  4325376u    // 128*768 fp32
#define CVEC_OFF 4718592u    // 128 fp32
#define PML_OFF  4719104u    // 32*16*8*2 fp32 = 32768
#define PO_OFF   4751872u    // 32*16*8*768 fp32 = 12582912
#define SK_OFF   17334784u   // 4*128*768 fp32 = 1572864 (split-K partials, reused)

__device__ __forceinline__ short f2bf(float x) {
  union { float f; unsigned u; } v; v.f = x;
  unsigned r = v.u + 0x7FFFu + ((v.u >> 16) & 1u);
  return (short)(r >> 16);
}

// async global->LDS, 16B per lane; LDS dest is wave-uniform base (HW adds lane*16)
#define GLOAD_LDS16(gp, lp) __builtin_amdgcn_global_load_lds( \
    (const __attribute__((address_space(1))) unsigned int*)(gp), \
    (__attribute__((address_space(3))) unsigned int*)(lp), 16, 0, 0)

// ---------------------------------------------------------------- prep: W converts + hbar (fused)
// blocks 0..431: wcvt (z = bx/144); blocks 432..559: hbar segment-mean
__global__ void k_prep(const float* __restrict__ Wt, const float* __restrict__ Wl,
                       short* __restrict__ Wtt, short* __restrict__ Wlt,
                       short* __restrict__ Wtb,
                       const float* __restrict__ hs, const int* __restrict__ lmask,
                       float* __restrict__ hbar) {
  __shared__ float tile[64][65];
  __shared__ int list[LL];
  __shared__ int nlist_s;
  int bx = blockIdx.x;
  int t = threadIdx.x;
  if (bx < 432) {
    int z = bx / 144, r = bx % 144;
    int kb = (r % 12) * 64, nb = (r / 12) * 64;
    int c = t & 63;
    int r0 = (t >> 6) * 16;
    if (z == 2) {
#pragma unroll
      for (int i = 0; i < 16; ++i) {
        int rr = kb + r0 + i;
        Wtb[(size_t)rr * DD + nb + c] = f2bf(Wt[(size_t)rr * DD + nb + c]);
      }
      return;
    }
    const float* src = z ? Wl : Wt;
    short* dst = z ? Wlt : Wtt;
#pragma unroll
    for (int i = 0; i < 16; ++i)
      tile[r0 + i][c] = src[(size_t)(kb + r0 + i) * DD + nb + c];
    __syncthreads();
#pragma unroll
    for (int i = 0; i < 16; ++i)
      dst[(size_t)(nb + r0 + i) * HH + kb + c] = f2bf(tile[c][r0 + i]);
    return;
  }
  int bh = bx - 432;                  // 0..127
  int b = bh >> 3, m = bh & 7;
  int lane = t & 63, w = t >> 6;
  if (w == 0) {                       // deterministic compaction
    int base = 0;
    for (int win = 0; win < LL / 64; ++win) {
      int l = win * 64 + lane;
      bool match = (lmask[b * LL + l] == m + 1);
      unsigned long long mk = __ballot(match);
      if (match) {
        int pos = base + (int)__popcll(mk & ((1ull << lane) - 1ull));
        list[pos] = l;
      }
      base += (int)__popcll(mk);
    }
    if (lane == 0) nlist_s = base;
  }
  __syncthreads();
  int n = nlist_s;
  float inv = 1.0f / (float)(n > 1 ? n : 1);
  float a0 = 0.f, a1 = 0.f, a2 = 0.f;
  for (int i = 0; i < n; ++i) {
    const float* rr = hs + (size_t)(b * LL + list[i]) * HH;
    a0 += rr[t]; a1 += rr[t + 256]; a2 += rr[t + 512];
  }
  float* dst = hbar + (size_t)(b * MM + m) * HH;
  dst[t] = a0 * inv; dst[t + 256] = a1 * inv; dst[t + 512] = a2 * inv;
}

// ---------------------------------------------------------------- split-K 128x768 GEMM (K=768/4)
// grid (6 N-tiles, 4 K-chunks); partials -> part[kc][128][768]; proven r6 body, NTK=3.
__global__ __launch_bounds__(256, 3)
void k_skgemm(const float* __restrict__ A, const short* __restrict__ Bt,
              float* __restrict__ part) {
  __shared__ short As[128][64];
  __shared__ short Bs[2][128][64];
  int t = threadIdx.x;
  int lane = t & 63, w = t >> 6;
  int wm = w >> 1, wn = w & 1;
  int n0 = blockIdx.x * 128;
  int kt0 = blockIdx.y * 3;

  f32x4 acc[4][4] = {};
  float4 areg[8];

  auto issueA = [&](int kt) {
    const float* Ag = A + (size_t)(kt0 + kt) * 64;
#pragma unroll
    for (int i = 0; i < 8; ++i) {
      int slot = i * 256 + t;
      int row = slot >> 4, c = slot & 15;
      areg[i] = *(const float4*)(Ag + (size_t)row * HH + c * 4);
    }
  };
  auto issueB = [&](int kt, int buf) {
    const short* Bg = Bt + (size_t)n0 * HH + (size_t)(kt0 + kt) * 64;
#pragma unroll
    for (int i = 0; i < 4; ++i) {
      int slot = i * 256 + w * 64 + lane;
      int row = slot >> 3, c = slot & 7;
      int cs = c ^ (row & 7);
      GLOAD_LDS16(Bg + (size_t)row * HH + cs * 8,
                  (char*)&Bs[0][0][0] + (size_t)buf * 16384 + (size_t)(i * 256 + w * 64) * 16);
    }
  };
  auto writeA = [&]() {
#pragma unroll
    for (int i = 0; i < 8; ++i) {
      int slot = i * 256 + t;
      int row = slot >> 4, c = slot & 15;
      unsigned d0, d1;
      asm("v_cvt_pk_bf16_f32 %0, %1, %2" : "=v"(d0) : "v"(areg[i].x), "v"(areg[i].y));
      asm("v_cvt_pk_bf16_f32 %0, %1, %2" : "=v"(d1) : "v"(areg[i].z), "v"(areg[i].w));
      int phys = (c >> 1) ^ (row & 7);
      uint2 val = {d0, d1};
      *(uint2*)((char*)&As[0][0] + (size_t)row * 128 + phys * 16 + (c & 1) * 8) = val;
    }
  };
  auto compute = [&](int buf) {
#pragma unroll
    for (int kk = 0; kk < 2; ++kk) {
      s16x8 a[4], bb[4];
#pragma unroll
      for (int i = 0; i < 4; ++i) {
        int row = wm * 64 + i * 16 + (lane & 15);
        int p = (kk * 4 + (lane >> 4)) ^ (row & 7);
        a[i] = *(const s16x8*)((const char*)&As[0][0] + (size_t)row * 128 + p * 16);
      }
#pragma unroll
      for (int i = 0; i < 4; ++i) {
        int row = wn * 64 + i * 16 + (lane & 15);
        int p = (kk * 4 + (lane >> 4)) ^ (row & 7);
        bb[i] = *(const s16x8*)((const char*)&Bs[0][0][0] + (size_t)buf * 16384 + (size_t)row * 128 + p * 16);
      }
#pragma unroll
      for (int mi = 0; mi < 4; ++mi)
#pragma unroll
        for (int ni = 0; ni < 4; ++ni)
          acc[mi][ni] = __builtin_amdgcn_mfma_f32_16x16x32_bf16(a[mi], bb[ni], acc[mi][ni], 0, 0, 0);
    }
  };

  issueA(0); issueB(0, 0);
  writeA();
  __syncthreads();
  for (int kt = 0; kt < 3; ++kt) {
    if (kt + 1 < 3) { issueA(kt + 1); issueB(kt + 1, (kt + 1) & 1); }
    compute(kt & 1);
    __syncthreads();
    if (kt + 1 < 3) {
      writeA();
      __syncthreads();
    }
  }

  float* po = part + (size_t)blockIdx.y * 128 * HH;
#pragma unroll
  for (int mi = 0; mi < 4; ++mi) {
    int row = wm * 64 + mi * 16 + ((lane >> 4) * 4);
#pragma unroll
    for (int ni = 0; ni < 4; ++ni) {
      int col = n0 + wn * 64 + ni * 16 + (lane & 15);
#pragma unroll
      for (int j = 0; j < 4; ++j)
        po[(size_t)(row + j) * HH + col] = acc[mi][ni][j];
    }
  }
}

// ---------------------------------------------------------------- reduce partials -> agg (+bl), cvec
__global__ void k_red_agg(const float* __restrict__ part, const float* __restrict__ bl,
                          const float* __restrict__ bt, float* __restrict__ out,
                          float* __restrict__ cvec) {
  int row = blockIdx.x;   // 128
  int t = threadIdx.x;    // 256
  int lane = t & 63, w = t >> 6;
  __shared__ float wred[4];
  float dotbt = 0.f;
#pragma unroll
  for (int cc = 0; cc < 3; ++cc) {
    int c = cc * 256 + t;
    float s = bl[c];
#pragma unroll
    for (int kc = 0; kc < 4; ++kc)
      s += part[((size_t)kc * 128 + row) * HH + c];
    out[O_AGGL + (size_t)row * DD + c] = s;
    dotbt += s * bt[c];
  }
  for (int sh = 32; sh; sh >>= 1) dotbt += __shfl_xor(dotbt, sh, 64);
  if (lane == 0) wred[w] = dotbt;
  __syncthreads();
  if (t == 0) cvec[row] = wred[0] + wred[1] + wred[2] + wred[3];
}

// ---------------------------------------------------------------- reduce partials -> qh
__global__ void k_red_qh(const float* __restrict__ part, float* __restrict__ qh) {
  int row = blockIdx.x;
  int t = threadIdx.x;
#pragma unroll
  for (int cc = 0; cc < 3; ++cc) {
    int c = cc * 256 + t;
    float s = 0.f;
#pragma unroll
    for (int kc = 0; kc < 4; ++kc)
      s += part[((size_t)kc * 128 + row) * HH + c];
    qh[(size_t)row * HH + c] = s;
  }
}

// ---------------------------------------------------------------- reduce partials -> aggregated_text (+bt)
__global__ void k_red_aggt(const float* __restrict__ part, const float* __restrict__ bt,
                           float* __restrict__ out) {
  int row = blockIdx.x;
  int t = threadIdx.x;
#pragma unroll
  for (int cc = 0; cc < 3; ++cc) {
    int c = cc * 256 + t;
    float s = bt[c];
#pragma unroll
    for (int kc = 0; kc < 4; ++kc)
      s += part[((size_t)kc * 128 + row) * HH + c];
    out[O_AGGT + (size_t)row * DD + c] = s;
  }
}

// ---------------------------------------------------------------- fused scores+softmax-partial+pool
__global__ __launch_bounds__(256, 3)
void k_attnpool(const float* __restrict__ hs, const float* __restrict__ qh,
                const float* __restrict__ cvec, const int* __restrict__ lmask,
                const int* __restrict__ amask, const float* __restrict__ temp_p,
                float* __restrict__ part_o, float* __restrict__ part_ml) {
  __shared__ short As[2][64][64];   // 16 KB
  __shared__ short Bs[16][776];     // 24.8 KB
  __shared__ float w_lds[64][8];    // 2 KB
  int chunk = blockIdx.x;           // 32
  int b = blockIdx.y;               // 16
  int t = threadIdx.x;
  int lane = t & 63, w = t >> 6;

  const float* qsrc = qh + (size_t)b * MM * HH;
  for (int c = t; c < HH; c += 256) {
#pragma unroll
    for (int r = 0; r < 8; ++r) Bs[r][c] = f2bf(qsrc[(size_t)r * HH + c]);
#pragma unroll
    for (int r = 8; r < 16; ++r) Bs[r][c] = 0;
  }

  const float* Hg = hs + (size_t)(b * LL + chunk * 64) * HH;
  float4 areg[4];
  auto issueA = [&](int kt) {
#pragma unroll
    for (int i = 0; i < 4; ++i) {
      int slot = i * 256 + t;
      int row = slot >> 4, c = slot & 15;
      areg[i] = *(const float4*)(Hg + (size_t)row * HH + kt * 64 + c * 4);
    }
  };
  auto writeA = [&](int buf) {
#pragma unroll
    for (int i = 0; i < 4; ++i) {
      int slot = i * 256 + t;
      int row = slot >> 4, c = slot & 15;
      unsigned d0, d1;
      asm("v_cvt_pk_bf16_f32 %0, %1, %2" : "=v"(d0) : "v"(areg[i].x), "v"(areg[i].y));
      asm("v_cvt_pk_bf16_f32 %0, %1, %2" : "=v"(d1) : "v"(areg[i].z), "v"(areg[i].w));
      int phys = (c >> 1) ^ (row & 7);
      uint2 val = {d0, d1};
      *(uint2*)((char*)&As[buf][0][0] + (size_t)row * 128 + phys * 16 + (c & 1) * 8) = val;
    }
  };

  f32x4 acc = {};
  issueA(0);
  writeA(0);
  __syncthreads();
  for (int kt = 0; kt < 12; ++kt) {
    if (kt + 1 < 12) issueA(kt + 1);
    int buf = kt & 1;
#pragma unroll
    for (int kk = 0; kk < 2; ++kk) {
      int arow = w * 16 + (lane & 15);
      int p = (kk * 4 + (lane >> 4)) ^ (arow & 7);
      s16x8 a = *(const s16x8*)((const char*)&As[buf][0][0] + (size_t)arow * 128 + p * 16);
      s16x8 bfr = *(const s16x8*)&Bs[lane & 15][kt * 64 + kk * 32 + (lane >> 4) * 8];
      acc = __builtin_amdgcn_mfma_f32_16x16x32_bf16(a, bfr, acc, 0, 0, 0);
    }
    if (kt + 1 < 12) writeA(buf ^ 1);
    __syncthreads();
  }

  float inv_temp = 1.0f / fmaxf(fabsf(temp_p[0]), 0.1f);
  int m = lane & 15;
  int tok0 = w * 16 + (lane >> 4) * 4;
  if (m < MM) {
    float cv = cvec[b * MM + m];
    int4 lm = *(const int4*)&lmask[b * LL + chunk * 64 + tok0];
    int4 am = *(const int4*)&amask[b * LL + chunk * 64 + tok0];
    w_lds[tok0 + 0][m] = (lm.x == 0 && am.x == 1) ? (acc[0] + cv) * inv_temp : -1e30f;
    w_lds[tok0 + 1][m] = (lm.y == 0 && am.y == 1) ? (acc[1] + cv) * inv_temp : -1e30f;
    w_lds[tok0 + 2][m] = (lm.z == 0 && am.z == 1) ? (acc[2] + cv) * inv_temp : -1e30f;
    w_lds[tok0 + 3][m] = (lm.w == 0 && am.w == 1) ? (acc[3] + cv) * inv_temp : -1e30f;
  }
  __syncthreads();

#pragma unroll
  for (int half = 0; half < 2; ++half) {
    int mm = w + half * 4;
    float v = w_lds[lane][mm];
    float mx = v;
    for (int s = 32; s; s >>= 1) mx = fmaxf(mx, __shfl_xor(mx, s, 64));
    float e = __expf(v - mx);
    float l = e;
    for (int s = 32; s; s >>= 1) l += __shfl_xor(l, s, 64);
    w_lds[lane][mm] = e;
    if (lane == 0) {
      float* pml = part_ml + ((size_t)(chunk * BB + b) * MM + mm) * 2;
      pml[0] = mx; pml[1] = l;
    }
  }
  __syncthreads();

  if (t < 192) {
    int h0 = t * 4;
    f32x4 o[8] = {};
    const float* hp = Hg + h0;
    for (int tok = 0; tok < 64; ++tok) {
      float4 hv = *(const float4*)(hp + (size_t)tok * HH);
      float4 w0 = *(const float4*)&w_lds[tok][0];
      float4 w1 = *(const float4*)&w_lds[tok][4];
      o[0][0] += w0.x * hv.x; o[0][1] += w0.x * hv.y; o[0][2] += w0.x * hv.z; o[0][3] += w0.x * hv.w;
      o[1][0] += w0.y * hv.x; o[1][1] += w0.y * hv.y; o[1][2] += w0.y * hv.z; o[1][3] += w0.y * hv.w;
      o[2][0] += w0.z * hv.x; o[2][1] += w0.z * hv.y; o[2][2] += w0.z * hv.z; o[2][3] += w0.z * hv.w;
      o[3][0] += w0.w * hv.x; o[3][1] += w0.w * hv.y; o[3][2] += w0.w * hv.z; o[3][3] += w0.w * hv.w;
      o[4][0] += w1.x * hv.x; o[4][1] += w1.x * hv.y; o[4][2] += w1.x * hv.z; o[4][3] += w1.x * hv.w;
      o[5][0] += w1.y * hv.x; o[5][1] += w1.y * hv.y; o[5][2] += w1.y * hv.z; o[5][3] += w1.y * hv.w;
      o[6][0] += w1.z * hv.x; o[6][1] += w1.z * hv.y; o[6][2] += w1.z * hv.z; o[6][3] += w1.z * hv.w;
      o[7][0] += w1.w * hv.x; o[7][1] += w1.w * hv.y; o[7][2] += w1.w * hv.z; o[7][3] += w1.w * hv.w;
    }
    float* po = part_o + (size_t)(chunk * BB + b) * MM * HH + h0;
#pragma unroll
    for (int mm = 0; mm < 8; ++mm)
      *(f32x4*)(po + (size_t)mm * HH) = o[mm];
  }
}

// ---------------------------------------------------------------- finish: flash-reduce partials -> hst
__global__ void k_finish(const float* __restrict__ part_o, const float* __restrict__ part_ml,
                         float* __restrict__ hst) {
  int row = blockIdx.x;    // 128
  int b = row >> 3, m = row & 7;
  int t = threadIdx.x;     // 192
  float mg = -1e30f;
#pragma unroll
  for (int lc = 0; lc < 32; ++lc)
    mg = fmaxf(mg, part_ml[((size_t)(lc * BB + b) * MM + m) * 2]);
  float L = 0.f;
  f32x4 acc = {};
  int h0 = t * 4;
  for (int lc = 0; lc < 32; ++lc) {
    const float* pml = part_ml + ((size_t)(lc * BB + b) * MM + m) * 2;
    float f = __expf(pml[0] - mg);
    L += pml[1] * f;
    f32x4 v = *(const f32x4*)(part_o + ((size_t)(lc * BB + b) * MM + m) * HH + h0);
    acc[0] += v[0] * f; acc[1] += v[1] * f; acc[2] += v[2] * f; acc[3] += v[3] * f;
  }
  float inv = 1.0f / L;
  f32x4 r = {acc[0] * inv, acc[1] * inv, acc[2] * inv, acc[3] * inv};
  *(f32x4*)(hst + (size_t)row * HH + h0) = r;
}

// ---------------------------------------------------------------- cosine head + ids + scale
__global__ void k_head(const float* __restrict__ lscale_p, float* __restrict__ out) {
  int row = blockIdx.x;
  int lane = threadIdx.x;
  const float* at = out + O_AGGT + (size_t)row * DD;
  const float* al = out + O_AGGL + (size_t)row * DD;
  float dot = 0.f, nt = 0.f, nl = 0.f;
  for (int i = lane; i < DD; i += 64) {
    float a = at[i], c = al[i];
    dot += a * c; nt += a * a; nl += c * c;
  }
  for (int s = 32; s; s >>= 1) {
    dot += __shfl_xor(dot, s, 64);
    nt  += __shfl_xor(nt, s, 64);
    nl  += __shfl_xor(nl, s, 64);
  }
  if (lane == 0) {
    float scale = expf(lscale_p[0]);
    float denom = fmaxf(sqrtf(nt), 1e-8f) * fmaxf(sqrtf(nl), 1e-8f);
    out[O_LOGITS + row] = dot / denom * scale;
    out[O_BID + row] = (float)(row >> 3);
    out[O_LID + row] = (float)((row & 7) + 1);
    if (row == 0) out[O_SCALE] = scale;
  }
}

extern "C" void kernel_launch(void* const* d_in, const int* in_sizes, int n_in,
                              void* d_out, int out_size, void* d_ws, size_t ws_size,
                              hipStream_t stream) {
  const float* hs    = (const float*)d_in[0];
  const float* Wt    = (const float*)d_in[1];
  const float* bt    = (const float*)d_in[2];
  const float* Wl    = (const float*)d_in[3];
  const float* bl    = (const float*)d_in[4];
  const float* atemp = (const float*)d_in[5];
  const float* lsc   = (const float*)d_in[6];
  const int*   lmask = (const int*)d_in[7];
  const int*   amask = (const int*)d_in[9];
  float* out = (float*)d_out;
  char* ws = (char*)d_ws;
  short* Wtt  = (short*)(ws + WTT_OFF);
  short* Wlt  = (short*)(ws + WLT_OFF);
  short* Wtb  = (short*)(ws + WTB_OFF);
  float* hbar = (float*)(ws + HBAR_OFF);
  float* qh   = (float*)(ws + QH_OFF);
  float* hst  = (float*)(ws + HST_OFF);
  float* cvec = (float*)(ws + CVEC_OFF);
  float* pml  = (float*)(ws + PML_OFF);
  float* po   = (float*)(ws + PO_OFF);
  float* skp  = (float*)(ws + SK_OFF);

  k_prep<<<560, 256, 0, stream>>>(Wt, Wl, Wtt, Wlt, Wtb, hs, lmask, hbar);
  k_skgemm<<<dim3(6, 4), 256, 0, stream>>>(hbar, Wlt, skp);
  k_red_agg<<<128, 256, 0, stream>>>(skp, bl, bt, out, cvec);
  k_skgemm<<<dim3(6, 4), 256, 0, stream>>>(out + O_AGGL, Wtb, skp);
  k_red_qh<<<128, 256, 0, stream>>>(skp, qh);
  k_attnpool<<<dim3(32, 16), 256, 0, stream>>>(hs, qh, cvec, lmask, amask, atemp, po, pml);
  k_finish<<<128, 192, 0, stream>>>(po, pml, hst);
  k_skgemm<<<dim3(6, 4), 256, 0, stream>>>(hst, Wtt, skp);
  k_red_aggt<<<128, 256, 0, stream>>>(skp, bt, out);
  k_head<<<128, 64, 0, stream>>>(lsc, out);
}